// Round 8
// baseline (13316.028 us; speedup 1.0000x reference)
//
#include <hip/hip_runtime.h>
#include <hip/hip_cooperative_groups.h>
#include <math.h>

namespace cg = cooperative_groups;

// Problem constants
#define B_    512
#define S_    128
#define H_    512
#define H3_   1536
#define IV_   8192
#define OUTC_ 129
#define CHUNK_ 11008       // 66048/6, divisible by 128
#define NCHUNK_ 6
#define EOS_  1

typedef __attribute__((ext_vector_type(8))) short  bf16x8;
typedef __attribute__((ext_vector_type(4))) float  f32x4;

__device__ inline unsigned short f2bf(float f) {
    union { float f; unsigned u; } x; x.f = f;
    unsigned r = x.u + 0x7FFF + ((x.u >> 16) & 1);   // RNE
    return (unsigned short)(r >> 16);
}
__device__ inline float bf2f(unsigned short b) {
    union { unsigned u; float f; } x; x.u = ((unsigned)b) << 16;
    return x.f;
}

// ---------------------------------------------------------------------------
// Generic f32 -> (hi,lo) bf16 split, optional relu first. n4 float4s.
template<bool RELU>
__global__ __launch_bounds__(256)
void split_f32(const float* __restrict__ src, unsigned short* __restrict__ hi,
               unsigned short* __restrict__ lo, int n4) {
    int i = blockIdx.x * 256 + threadIdx.x;
    if (i >= n4) return;
    float4 v = *(const float4*)&src[(size_t)i * 4];
    float a[4] = {v.x, v.y, v.z, v.w};
    size_t off = (size_t)i * 4;
    #pragma unroll
    for (int q = 0; q < 4; ++q) {
        float f = RELU ? fmaxf(a[q], 0.f) : a[q];
        unsigned short h = f2bf(f);
        hi[off + q] = h;
        lo[off + q] = f2bf(f - bf2f(h));
    }
}

// ---------------------------------------------------------------------------
// h0 gather + split
__global__ __launch_bounds__(256)
void build_h0_split(const int* __restrict__ stem, const float* __restrict__ stem_emb,
                    unsigned short* __restrict__ Hh, unsigned short* __restrict__ Hl) {
    int i = blockIdx.x * 256 + threadIdx.x;   // over B*H/4
    int b = i >> 7;
    int c = (i & 127) << 2;
    float4 v = *(const float4*)&stem_emb[(size_t)stem[b] * H_ + c];
    float a[4] = {v.x, v.y, v.z, v.w};
    size_t off = (size_t)b * H_ + c;
    #pragma unroll
    for (int q = 0; q < 4; ++q) {
        unsigned short h = f2bf(a[q]);
        Hh[off + q] = h;
        Hl[off + q] = f2bf(a[q] - bf2f(h));
    }
}

// ---------------------------------------------------------------------------
// Split-precision NT GEMM: C = (Ah+Al) @ (Wh+Wl)^T + bias, via 3 MFMA passes
// (hi*hi + lo*hi + hi*lo). A:[M,K], W:[N,K] bf16 planes. 128x128 tile, 256 thr.
// OUT_MODE 0: f32 C. OUT_MODE 1: write (hi,lo) bf16 split planes.
template<int OUT_MODE, bool RELU_OUT>
__global__ __launch_bounds__(256)
void gemm_split(const unsigned short* __restrict__ Ah, const unsigned short* __restrict__ Al,
                const unsigned short* __restrict__ Wh, const unsigned short* __restrict__ Wl,
                const float* __restrict__ bias,
                float* __restrict__ Cf, unsigned short* __restrict__ Chi,
                unsigned short* __restrict__ Clo, int M, int N, int K) {
    __shared__ unsigned short As[128][72];   // pad: 2-way bank alias (free)
    __shared__ unsigned short Ws[128][72];
    const int tid = threadIdx.x;
    const int bm = blockIdx.y * 128, bn = blockIdx.x * 128;
    const int wid = tid >> 6, lane = tid & 63;
    const int wm = (wid >> 1) * 64, wn = (wid & 1) * 64;
    const int lr = lane & 15, kg = (lane >> 4) * 8;

    f32x4 acc[4][4];
    #pragma unroll
    for (int i = 0; i < 4; ++i)
        #pragma unroll
        for (int j = 0; j < 4; ++j) acc[i][j] = f32x4{0.f, 0.f, 0.f, 0.f};

    for (int ph = 0; ph < 3; ++ph) {
        const unsigned short* Ap = (ph == 1) ? Al : Ah;
        const unsigned short* Wp = (ph == 2) ? Wl : Wh;
        for (int k0 = 0; k0 < K; k0 += 64) {
            int4 av[4], wv[4];
            #pragma unroll
            for (int s = 0; s < 4; ++s) {
                int seg = s * 256 + tid;            // 1024 16B segs per tile
                int row = seg >> 3, c8 = (seg & 7) * 8;
                av[s] = *(const int4*)&Ap[(size_t)(bm + row) * K + k0 + c8];
                wv[s] = *(const int4*)&Wp[(size_t)(bn + row) * K + k0 + c8];
            }
            __syncthreads();
            #pragma unroll
            for (int s = 0; s < 4; ++s) {
                int seg = s * 256 + tid;
                int row = seg >> 3, c8 = (seg & 7) * 8;
                *(int4*)&As[row][c8] = av[s];
                *(int4*)&Ws[row][c8] = wv[s];
            }
            __syncthreads();
            #pragma unroll
            for (int ks = 0; ks < 2; ++ks) {
                bf16x8 af[4], bfr[4];
                #pragma unroll
                for (int i = 0; i < 4; ++i)
                    af[i] = *(const bf16x8*)&As[wm + i * 16 + lr][ks * 32 + kg];
                #pragma unroll
                for (int j = 0; j < 4; ++j)
                    bfr[j] = *(const bf16x8*)&Ws[wn + j * 16 + lr][ks * 32 + kg];
                #pragma unroll
                for (int i = 0; i < 4; ++i)
                    #pragma unroll
                    for (int j = 0; j < 4; ++j)
                        acc[i][j] = __builtin_amdgcn_mfma_f32_16x16x32_bf16(
                            af[i], bfr[j], acc[i][j], 0, 0, 0);
            }
        }
    }

    const int r0 = (lane >> 4) * 4, cn = lane & 15;
    #pragma unroll
    for (int i = 0; i < 4; ++i) {
        #pragma unroll
        for (int j = 0; j < 4; ++j) {
            int colg = bn + wn + j * 16 + cn;
            float bv = bias[colg];
            #pragma unroll
            for (int rg = 0; rg < 4; ++rg) {
                int rowg = bm + wm + i * 16 + r0 + rg;
                float v = acc[i][j][rg] + bv;
                if (RELU_OUT) v = fmaxf(v, 0.f);
                size_t off = (size_t)rowg * N + colg;
                if (OUT_MODE == 0) {
                    Cf[off] = v;
                } else {
                    unsigned short h = f2bf(v);
                    Chi[off] = h;
                    Clo[off] = f2bf(v - bf2f(h));
                }
            }
        }
    }
}

// ---------------------------------------------------------------------------
// Persistent cooperative GRU: the WHOLE 129-step recurrence in one launch.
// Grid: 32 j-blocks (BN=16 cols, 48 W rows) x 8 b-blocks (BM=64 rows) = 256
// blocks, 256 thr (4 waves; wave w owns rows w*16..w*16+15). Per K-chunk
// (K=64): stage A(hi,lo) + W(hi,lo) once, run all 3 split passes. Ping-pong
// h buffers; one grid.sync() per step (read buf a, write buf o: race-free).
__global__ __launch_bounds__(256)
void gru_persist(const int* __restrict__ goal,
                 unsigned short* __restrict__ Hh0, unsigned short* __restrict__ Hl0,
                 unsigned short* __restrict__ Hh1, unsigned short* __restrict__ Hl1,
                 unsigned short* __restrict__ RHh, unsigned short* __restrict__ RHl,
                 const unsigned short* __restrict__ Wh, const unsigned short* __restrict__ Wl,
                 const float* __restrict__ GW, const float* __restrict__ b_hh) {
    cg::grid_group grid = cg::this_grid();
    __shared__ unsigned short Ahs[64][72];
    __shared__ unsigned short Als[64][72];
    __shared__ unsigned short Whs[48][72];
    __shared__ unsigned short Wls[48][72];
    const int tid = threadIdx.x;
    const int bn = blockIdx.x * 16;        // j block (16 cols)
    const int bm = blockIdx.y * 64;        // batch block (64 rows)
    const int w = tid >> 6, lane = tid & 63;
    const int lr = lane & 15, kg = (lane >> 4) * 8;
    const int r0 = (lane >> 4) * 4, cn = lane & 15;

    for (int t = 0; t <= S_; ++t) {
        const unsigned short* Hih = (t & 1) ? Hh1 : Hh0;
        const unsigned short* Hil = (t & 1) ? Hl1 : Hl0;
        unsigned short* Hoh = (t & 1) ? Hh0 : Hh1;
        unsigned short* Hol = (t & 1) ? Hl0 : Hl1;

        f32x4 acc[3];
        #pragma unroll
        for (int f = 0; f < 3; ++f) acc[f] = f32x4{0.f, 0.f, 0.f, 0.f};

        for (int k0 = 0; k0 < H_; k0 += 64) {
            int4 ahv[2], alv[2], whv[2], wlv[2];
            #pragma unroll
            for (int s = 0; s < 2; ++s) {            // A: 64x64 = 512 segs
                int seg = s * 256 + tid;
                int row = seg >> 3, c8 = (seg & 7) * 8;
                ahv[s] = *(const int4*)&Hih[(size_t)(bm + row) * H_ + k0 + c8];
                alv[s] = *(const int4*)&Hil[(size_t)(bm + row) * H_ + k0 + c8];
            }
            #pragma unroll
            for (int s = 0; s < 2; ++s) {            // W: 48x64 = 384 segs
                int seg = s * 256 + tid;
                if (seg < 384) {
                    int wr = seg >> 3, c8 = (seg & 7) * 8;
                    int grow = ((wr >> 4) << 9) + bn + (wr & 15);  // gate*512+bn+j
                    whv[s] = *(const int4*)&Wh[(size_t)grow * H_ + k0 + c8];
                    wlv[s] = *(const int4*)&Wl[(size_t)grow * H_ + k0 + c8];
                }
            }
            __syncthreads();   // previous chunk's LDS reads done
            #pragma unroll
            for (int s = 0; s < 2; ++s) {
                int seg = s * 256 + tid;
                int row = seg >> 3, c8 = (seg & 7) * 8;
                *(int4*)&Ahs[row][c8] = ahv[s];
                *(int4*)&Als[row][c8] = alv[s];
            }
            #pragma unroll
            for (int s = 0; s < 2; ++s) {
                int seg = s * 256 + tid;
                if (seg < 384) {
                    int wr = seg >> 3, c8 = (seg & 7) * 8;
                    *(int4*)&Whs[wr][c8] = whv[s];
                    *(int4*)&Wls[wr][c8] = wlv[s];
                }
            }
            __syncthreads();
            #pragma unroll
            for (int ks = 0; ks < 2; ++ks) {
                bf16x8 afh, afl, bfh[3], bfl[3];
                afh = *(const bf16x8*)&Ahs[w * 16 + lr][ks * 32 + kg];
                afl = *(const bf16x8*)&Als[w * 16 + lr][ks * 32 + kg];
                #pragma unroll
                for (int f = 0; f < 3; ++f) {
                    bfh[f] = *(const bf16x8*)&Whs[f * 16 + lr][ks * 32 + kg];
                    bfl[f] = *(const bf16x8*)&Wls[f * 16 + lr][ks * 32 + kg];
                }
                #pragma unroll
                for (int f = 0; f < 3; ++f) {
                    acc[f] = __builtin_amdgcn_mfma_f32_16x16x32_bf16(afh, bfh[f], acc[f], 0, 0, 0);
                    acc[f] = __builtin_amdgcn_mfma_f32_16x16x32_bf16(afl, bfh[f], acc[f], 0, 0, 0);
                    acc[f] = __builtin_amdgcn_mfma_f32_16x16x32_bf16(afh, bfl[f], acc[f], 0, 0, 0);
                }
            }
        }

        // Epilogue: gates. acc[f]: f=gate, C row = w*16 + r0 + rg, col = bn+cn.
        int j = bn + cn;
        float bhr = b_hh[j], bhz = b_hh[512 + j], bhn = b_hh[1024 + j];
        #pragma unroll
        for (int rg = 0; rg < 4; ++rg) {
            int b = bm + w * 16 + r0 + rg;
            int tok = (t < S_) ? goal[(size_t)b * S_ + t] : EOS_;
            const float* gw = GW + (size_t)tok * H3_;
            float rp = acc[0][rg] + bhr;
            float zp = acc[1][rg] + bhz;
            float hn = acc[2][rg] + bhn;
            float r = 1.f / (1.f + expf(-(gw[j] + rp)));
            float z = 1.f / (1.f + expf(-(gw[512 + j] + zp)));
            float n = tanhf(gw[1024 + j] + r * hn);
            size_t off = (size_t)b * H_ + j;
            float hp = bf2f(Hih[off]) + bf2f(Hil[off]);
            float hv = (1.f - z) * n + z * hp;
            unsigned short hh = f2bf(hv);
            Hoh[off] = hh;
            Hol[off] = f2bf(hv - bf2f(hh));
            float rv = fmaxf(hv, 0.f);
            unsigned short rh = f2bf(rv);
            size_t roff = ((size_t)t * B_ + b) * H_ + j;
            RHh[roff] = rh;
            RHl[roff] = f2bf(rv - bf2f(rh));
        }
        __threadfence();   // make h_next visible device-wide before barrier
        grid.sync();
    }
}

// ---------------------------------------------------------------------------
// logit[row] = Y2[row][:] . out_W + out_b, scattered to d_out[b][pos].
__global__ __launch_bounds__(256)
void gemv_out(const float* __restrict__ Y2, const float* __restrict__ outW,
              const float* __restrict__ outb, float* __restrict__ out, int row0) {
    int wave = threadIdx.x >> 6;
    int lane = threadIdx.x & 63;
    int row = blockIdx.x * 4 + wave;
    const float* y = Y2 + (size_t)row * H_;
    float4 v0 = *(const float4*)&y[lane * 4];
    float4 v1 = *(const float4*)&y[256 + lane * 4];
    float4 w0 = *(const float4*)&outW[lane * 4];
    float4 w1 = *(const float4*)&outW[256 + lane * 4];
    float s = v0.x * w0.x + v0.y * w0.y + v0.z * w0.z + v0.w * w0.w
            + v1.x * w1.x + v1.y * w1.y + v1.z * w1.z + v1.w * w1.w;
    #pragma unroll
    for (int off = 32; off > 0; off >>= 1) s += __shfl_down(s, off);
    if (lane == 0) {
        int r = row0 + row;
        int t = r / B_;
        int b = r - t * B_;
        int pos = (t == S_) ? 0 : t + 1;
        out[(size_t)b * OUTC_ + pos] = s + outb[0];
    }
}

// ---------------------------------------------------------------------------
__global__ __launch_bounds__(64)
void logsoftmax_rows(float* __restrict__ out) {
    int b = blockIdx.x;
    int lane = threadIdx.x;
    float* row = out + (size_t)b * OUTC_;
    float x0 = row[lane];
    float x1 = row[lane + 64];
    float x2 = (lane == 0) ? row[128] : -INFINITY;
    float m = fmaxf(fmaxf(x0, x1), x2);
    #pragma unroll
    for (int off = 32; off > 0; off >>= 1) m = fmaxf(m, __shfl_xor(m, off));
    float s = expf(x0 - m) + expf(x1 - m) + ((lane == 0) ? expf(x2 - m) : 0.f);
    #pragma unroll
    for (int off = 32; off > 0; off >>= 1) s += __shfl_xor(s, off);
    float ls = m + logf(s);
    row[lane] = x0 - ls;
    row[lane + 64] = x1 - ls;
    if (lane == 0) row[128] = x2 - ls;
}

// ---------------------------------------------------------------------------
extern "C" void kernel_launch(void* const* d_in, const int* in_sizes, int n_in,
                              void* d_out, int out_size, void* d_ws, size_t ws_size,
                              hipStream_t stream) {
    const int*   goal     = (const int*)d_in[0];
    const int*   stem     = (const int*)d_in[1];
    const float* stem_emb = (const float*)d_in[2];
    const float* word_emb = (const float*)d_in[3];
    const float* W_ih     = (const float*)d_in[4];
    const float* W_hh     = (const float*)d_in[5];
    const float* b_ih     = (const float*)d_in[6];
    const float* b_hh     = (const float*)d_in[7];
    const float* in_W     = (const float*)d_in[8];
    const float* in_b     = (const float*)d_in[9];
    const float* l0_W     = (const float*)d_in[10];
    const float* l0_b     = (const float*)d_in[11];
    const float* out_W    = (const float*)d_in[12];
    const float* out_b    = (const float*)d_in[13];
    float* out = (float*)d_out;

    // ~238 MB workspace layout (proven-good budget; see round-2/5 notes).
    char* base = (char*)d_ws;
    auto alloc = [&](size_t bytes) -> char* {
        char* p = base; base += (bytes + 255) & ~(size_t)255; return p;
    };
    // --- persistent region ---
    float* GW            = (float*)alloc((size_t)IV_ * H3_ * 4);           // 50.3 MB
    unsigned short* RHh  = (unsigned short*)alloc((size_t)(S_ + 1) * B_ * H_ * 2); // 67.7
    unsigned short* RHl  = (unsigned short*)alloc((size_t)(S_ + 1) * B_ * H_ * 2); // 67.7
    unsigned short* WHHh = (unsigned short*)alloc((size_t)H3_ * H_ * 2);   // 1.6
    unsigned short* WHHl = (unsigned short*)alloc((size_t)H3_ * H_ * 2);   // 1.6
    unsigned short* INWh = (unsigned short*)alloc((size_t)H_ * H_ * 2);
    unsigned short* INWl = (unsigned short*)alloc((size_t)H_ * H_ * 2);
    unsigned short* L0Wh = (unsigned short*)alloc((size_t)H_ * H_ * 2);
    unsigned short* L0Wl = (unsigned short*)alloc((size_t)H_ * H_ * 2);
    unsigned short* Hh0  = (unsigned short*)alloc((size_t)B_ * H_ * 2);
    unsigned short* Hl0  = (unsigned short*)alloc((size_t)B_ * H_ * 2);
    unsigned short* Hh1  = (unsigned short*)alloc((size_t)B_ * H_ * 2);
    unsigned short* Hl1  = (unsigned short*)alloc((size_t)B_ * H_ * 2);
    // --- union region: {RWE,WIH} (GW phase)  vs  {Y1,Y2} (MLP phase) ---
    char* uni = alloc((size_t)CHUNK_ * H_ * (2 + 2 + 4));                  // 45.1 MB
    unsigned short* RWEh = (unsigned short*)uni;
    unsigned short* RWEl = RWEh + (size_t)IV_ * H_;
    unsigned short* WIHh = RWEl + (size_t)IV_ * H_;
    unsigned short* WIHl = WIHh + (size_t)H3_ * H_;
    unsigned short* Y1h  = (unsigned short*)uni;
    unsigned short* Y1l  = Y1h + (size_t)CHUNK_ * H_;
    float* Y2            = (float*)(Y1l + (size_t)CHUNK_ * H_);

    // Splits of inputs
    split_f32<true ><<<(IV_ * H_ / 4) / 256, 256, 0, stream>>>(word_emb, RWEh, RWEl, IV_ * H_ / 4);
    split_f32<false><<<(H3_ * H_ / 4) / 256, 256, 0, stream>>>(W_ih, WIHh, WIHl, H3_ * H_ / 4);
    split_f32<false><<<(H3_ * H_ / 4) / 256, 256, 0, stream>>>(W_hh, WHHh, WHHl, H3_ * H_ / 4);
    split_f32<false><<<(H_ * H_ / 4) / 256, 256, 0, stream>>>(in_W, INWh, INWl, H_ * H_ / 4);
    split_f32<false><<<(H_ * H_ / 4) / 256, 256, 0, stream>>>(l0_W, L0Wh, L0Wl, H_ * H_ / 4);

    build_h0_split<<<(B_ * H_ / 4) / 256, 256, 0, stream>>>(stem, stem_emb, Hh0, Hl0);

    // GW = relu(word_emb) @ W_ih^T + b_ih   [8192 x 1536] f32
    gemm_split<0, false><<<dim3(H3_ / 128, IV_ / 128), 256, 0, stream>>>(
        RWEh, RWEl, WIHh, WIHl, b_ih, GW, nullptr, nullptr, IV_, H3_, H_);

    // Entire 129-step recurrence in ONE cooperative launch.
    {
        void* kargs[] = {
            (void*)&goal, (void*)&Hh0, (void*)&Hl0, (void*)&Hh1, (void*)&Hl1,
            (void*)&RHh, (void*)&RHl, (void*)&WHHh, (void*)&WHHl,
            (void*)&GW, (void*)&b_hh
        };
        hipLaunchCooperativeKernel((const void*)gru_persist, dim3(32, 8), dim3(256),
                                   kargs, 0, stream);
    }

    // MLP head over 66048 relu'd states, chunked 6x.
    for (int c = 0; c < NCHUNK_; ++c) {
        size_t ro = (size_t)c * CHUNK_ * H_;
        gemm_split<1, true><<<dim3(H_ / 128, CHUNK_ / 128), 256, 0, stream>>>(
            RHh + ro, RHl + ro, INWh, INWl, in_b, nullptr, Y1h, Y1l, CHUNK_, H_, H_);
        gemm_split<0, true><<<dim3(H_ / 128, CHUNK_ / 128), 256, 0, stream>>>(
            Y1h, Y1l, L0Wh, L0Wl, l0_b, Y2, nullptr, nullptr, CHUNK_, H_, H_);
        gemv_out<<<CHUNK_ / 4, 256, 0, stream>>>(Y2, out_W, out_b, out, c * CHUNK_);
    }

    logsoftmax_rows<<<B_, 64, 0, stream>>>(out);
}

// Round 9
// 12831.926 us; speedup vs baseline: 1.0377x; 1.0377x over previous
//
#include <hip/hip_runtime.h>
#include <math.h>

// Problem constants
#define B_    512
#define S_    128
#define H_    512
#define H3_   1536
#define IV_   8192
#define OUTC_ 129
#define CHUNK_ 11008       // 66048/6, divisible by 128
#define NCHUNK_ 6
#define EOS_  1

typedef __attribute__((ext_vector_type(8))) short  bf16x8;
typedef __attribute__((ext_vector_type(4))) float  f32x4;

__device__ inline unsigned short f2bf(float f) {
    union { float f; unsigned u; } x; x.f = f;
    unsigned r = x.u + 0x7FFF + ((x.u >> 16) & 1);   // RNE
    return (unsigned short)(r >> 16);
}
__device__ inline float bf2f(unsigned short b) {
    union { unsigned u; float f; } x; x.u = ((unsigned)b) << 16;
    return x.f;
}

// ---------------------------------------------------------------------------
// Generic f32 -> (hi,lo) bf16 split, optional relu first. n4 float4s.
template<bool RELU>
__global__ __launch_bounds__(256)
void split_f32(const float* __restrict__ src, unsigned short* __restrict__ hi,
               unsigned short* __restrict__ lo, int n4) {
    int i = blockIdx.x * 256 + threadIdx.x;
    if (i >= n4) return;
    float4 v = *(const float4*)&src[(size_t)i * 4];
    float a[4] = {v.x, v.y, v.z, v.w};
    size_t off = (size_t)i * 4;
    #pragma unroll
    for (int q = 0; q < 4; ++q) {
        float f = RELU ? fmaxf(a[q], 0.f) : a[q];
        unsigned short h = f2bf(f);
        hi[off + q] = h;
        lo[off + q] = f2bf(f - bf2f(h));
    }
}

// ---------------------------------------------------------------------------
// h0 gather + split
__global__ __launch_bounds__(256)
void build_h0_split(const int* __restrict__ stem, const float* __restrict__ stem_emb,
                    unsigned short* __restrict__ Hh, unsigned short* __restrict__ Hl) {
    int i = blockIdx.x * 256 + threadIdx.x;   // over B*H/4
    int b = i >> 7;
    int c = (i & 127) << 2;
    float4 v = *(const float4*)&stem_emb[(size_t)stem[b] * H_ + c];
    float a[4] = {v.x, v.y, v.z, v.w};
    size_t off = (size_t)b * H_ + c;
    #pragma unroll
    for (int q = 0; q < 4; ++q) {
        unsigned short h = f2bf(a[q]);
        Hh[off + q] = h;
        Hl[off + q] = f2bf(a[q] - bf2f(h));
    }
}

// ---------------------------------------------------------------------------
// Split-precision NT GEMM: C = (Ah+Al) @ (Wh+Wl)^T + bias, via 3 MFMA passes
// (hi*hi + lo*hi + hi*lo). A:[M,K], W:[N,K] bf16 planes. 128x128 tile, 256 thr.
// OUT_MODE 0: f32 C. OUT_MODE 1: write (hi,lo) bf16 split planes.
template<int OUT_MODE, bool RELU_OUT>
__global__ __launch_bounds__(256)
void gemm_split(const unsigned short* __restrict__ Ah, const unsigned short* __restrict__ Al,
                const unsigned short* __restrict__ Wh, const unsigned short* __restrict__ Wl,
                const float* __restrict__ bias,
                float* __restrict__ Cf, unsigned short* __restrict__ Chi,
                unsigned short* __restrict__ Clo, int M, int N, int K) {
    __shared__ unsigned short As[128][72];   // pad: 2-way bank alias (free)
    __shared__ unsigned short Ws[128][72];
    const int tid = threadIdx.x;
    const int bm = blockIdx.y * 128, bn = blockIdx.x * 128;
    const int wid = tid >> 6, lane = tid & 63;
    const int wm = (wid >> 1) * 64, wn = (wid & 1) * 64;
    const int lr = lane & 15, kg = (lane >> 4) * 8;

    f32x4 acc[4][4];
    #pragma unroll
    for (int i = 0; i < 4; ++i)
        #pragma unroll
        for (int j = 0; j < 4; ++j) acc[i][j] = f32x4{0.f, 0.f, 0.f, 0.f};

    for (int ph = 0; ph < 3; ++ph) {
        const unsigned short* Ap = (ph == 1) ? Al : Ah;
        const unsigned short* Wp = (ph == 2) ? Wl : Wh;
        for (int k0 = 0; k0 < K; k0 += 64) {
            int4 av[4], wv[4];
            #pragma unroll
            for (int s = 0; s < 4; ++s) {
                int seg = s * 256 + tid;            // 1024 16B segs per tile
                int row = seg >> 3, c8 = (seg & 7) * 8;
                av[s] = *(const int4*)&Ap[(size_t)(bm + row) * K + k0 + c8];
                wv[s] = *(const int4*)&Wp[(size_t)(bn + row) * K + k0 + c8];
            }
            __syncthreads();
            #pragma unroll
            for (int s = 0; s < 4; ++s) {
                int seg = s * 256 + tid;
                int row = seg >> 3, c8 = (seg & 7) * 8;
                *(int4*)&As[row][c8] = av[s];
                *(int4*)&Ws[row][c8] = wv[s];
            }
            __syncthreads();
            #pragma unroll
            for (int ks = 0; ks < 2; ++ks) {
                bf16x8 af[4], bfr[4];
                #pragma unroll
                for (int i = 0; i < 4; ++i)
                    af[i] = *(const bf16x8*)&As[wm + i * 16 + lr][ks * 32 + kg];
                #pragma unroll
                for (int j = 0; j < 4; ++j)
                    bfr[j] = *(const bf16x8*)&Ws[wn + j * 16 + lr][ks * 32 + kg];
                #pragma unroll
                for (int i = 0; i < 4; ++i)
                    #pragma unroll
                    for (int j = 0; j < 4; ++j)
                        acc[i][j] = __builtin_amdgcn_mfma_f32_16x16x32_bf16(
                            af[i], bfr[j], acc[i][j], 0, 0, 0);
            }
        }
    }

    const int r0 = (lane >> 4) * 4, cn = lane & 15;
    #pragma unroll
    for (int i = 0; i < 4; ++i) {
        #pragma unroll
        for (int j = 0; j < 4; ++j) {
            int colg = bn + wn + j * 16 + cn;
            float bv = bias[colg];
            #pragma unroll
            for (int rg = 0; rg < 4; ++rg) {
                int rowg = bm + wm + i * 16 + r0 + rg;
                float v = acc[i][j][rg] + bv;
                if (RELU_OUT) v = fmaxf(v, 0.f);
                size_t off = (size_t)rowg * N + colg;
                if (OUT_MODE == 0) {
                    Cf[off] = v;
                } else {
                    unsigned short h = f2bf(v);
                    Chi[off] = h;
                    Clo[off] = f2bf(v - bf2f(h));
                }
            }
        }
    }
}

// ---------------------------------------------------------------------------
// Block-local persistent GRU: batch rows are independent across the whole
// recurrence, so each block owns 16 rows for ALL 129 steps. h lives in LDS
// (double-buffered, bf16 hi/lo planes); the ONLY per-step sync is
// __syncthreads() (CU-local — no cross-XCD fence, no L2 flush, W_hh stays
// L2-resident). 32 blocks x 1024 thr (16 waves). Wave w owns j-tiles
// {2w, 2w+1} (16 cols each, all 3 gates). A-frags from LDS; B-frags (W rows)
// straight from global (L2-hot after step 0). Epilogue: gates + write
// relu(h) split to RH and h_next split to the other LDS buffer.
__global__ __launch_bounds__(1024)
void gru_local(const int* __restrict__ goal,
               const unsigned short* __restrict__ Hh0, const unsigned short* __restrict__ Hl0,
               unsigned short* __restrict__ RHh, unsigned short* __restrict__ RHl,
               const unsigned short* __restrict__ Wh, const unsigned short* __restrict__ Wl,
               const float* __restrict__ GW, const float* __restrict__ b_hh) {
    __shared__ unsigned short hbuf[2][2][16][520];   // [buf][plane][row][col+pad]
    const int tid = threadIdx.x;
    const int bm = blockIdx.x * 16;
    const int w = tid >> 6, lane = tid & 63;
    const int lr = lane & 15;           // A row / B col / C col
    const int kg = (lane >> 4) * 8;     // k offset within 32-chunk
    const int r0 = (lane >> 4) * 4;     // C row base

    // Stage h0 (16 rows x 512 x 2 planes = 2048 16B segs, 1024 threads)
    #pragma unroll
    for (int s = 0; s < 2; ++s) {
        int idx = s * 1024 + tid;
        int plane = idx >> 10;
        int seg = idx & 1023;
        int r = seg >> 6, c8 = (seg & 63) * 8;
        const unsigned short* src = plane ? Hl0 : Hh0;
        *(int4*)&hbuf[0][plane][r][c8] = *(const int4*)&src[(size_t)(bm + r) * H_ + c8];
    }

    const int ja = (w * 2) * 16 + lr;        // j for tile 0
    const int jb = ja + 16;                  // j for tile 1
    const float bAr = b_hh[ja], bAz = b_hh[512 + ja], bAn = b_hh[1024 + ja];
    const float bBr = b_hh[jb], bBz = b_hh[512 + jb], bBn = b_hh[1024 + jb];
    __syncthreads();

    for (int t = 0; t <= S_; ++t) {
        const int p = t & 1;
        #pragma unroll
        for (int jj = 0; jj < 2; ++jj) {
            const int j = jj ? jb : ja;
            const float br = jj ? bBr : bAr;
            const float bz = jj ? bBz : bAz;
            const float bn = jj ? bBn : bAn;
            f32x4 acc0 = {0.f, 0.f, 0.f, 0.f};
            f32x4 acc1 = {0.f, 0.f, 0.f, 0.f};
            f32x4 acc2 = {0.f, 0.f, 0.f, 0.f};
            #pragma unroll 4
            for (int kc = 0; kc < 16; ++kc) {
                bf16x8 ah = *(const bf16x8*)&hbuf[p][0][lr][kc * 32 + kg];
                bf16x8 al = *(const bf16x8*)&hbuf[p][1][lr][kc * 32 + kg];
                size_t o0 = (size_t)j * H_ + kc * 32 + kg;
                bf16x8 b0h = *(const bf16x8*)&Wh[o0];
                bf16x8 b0l = *(const bf16x8*)&Wl[o0];
                bf16x8 b1h = *(const bf16x8*)&Wh[o0 + (size_t)512 * H_];
                bf16x8 b1l = *(const bf16x8*)&Wl[o0 + (size_t)512 * H_];
                bf16x8 b2h = *(const bf16x8*)&Wh[o0 + (size_t)1024 * H_];
                bf16x8 b2l = *(const bf16x8*)&Wl[o0 + (size_t)1024 * H_];
                acc0 = __builtin_amdgcn_mfma_f32_16x16x32_bf16(ah, b0h, acc0, 0, 0, 0);
                acc0 = __builtin_amdgcn_mfma_f32_16x16x32_bf16(al, b0h, acc0, 0, 0, 0);
                acc0 = __builtin_amdgcn_mfma_f32_16x16x32_bf16(ah, b0l, acc0, 0, 0, 0);
                acc1 = __builtin_amdgcn_mfma_f32_16x16x32_bf16(ah, b1h, acc1, 0, 0, 0);
                acc1 = __builtin_amdgcn_mfma_f32_16x16x32_bf16(al, b1h, acc1, 0, 0, 0);
                acc1 = __builtin_amdgcn_mfma_f32_16x16x32_bf16(ah, b1l, acc1, 0, 0, 0);
                acc2 = __builtin_amdgcn_mfma_f32_16x16x32_bf16(ah, b2h, acc2, 0, 0, 0);
                acc2 = __builtin_amdgcn_mfma_f32_16x16x32_bf16(al, b2h, acc2, 0, 0, 0);
                acc2 = __builtin_amdgcn_mfma_f32_16x16x32_bf16(ah, b2l, acc2, 0, 0, 0);
            }
            // Epilogue: gates for 4 rows x this j.
            #pragma unroll
            for (int rg = 0; rg < 4; ++rg) {
                int row = r0 + rg;
                int b = bm + row;
                int tok = (t < S_) ? goal[b * S_ + t] : EOS_;
                const float* gw = GW + (size_t)tok * H3_;
                float rr = 1.f / (1.f + expf(-(gw[j] + acc0[rg] + br)));
                float zz = 1.f / (1.f + expf(-(gw[512 + j] + acc1[rg] + bz)));
                float nn = tanhf(gw[1024 + j] + rr * (acc2[rg] + bn));
                float hp = bf2f(hbuf[p][0][row][j]) + bf2f(hbuf[p][1][row][j]);
                float hv = (1.f - zz) * nn + zz * hp;
                unsigned short hh = f2bf(hv);
                hbuf[p ^ 1][0][row][j] = hh;
                hbuf[p ^ 1][1][row][j] = f2bf(hv - bf2f(hh));
                float rv = fmaxf(hv, 0.f);
                unsigned short rh = f2bf(rv);
                size_t roff = ((size_t)t * B_ + b) * H_ + j;
                RHh[roff] = rh;
                RHl[roff] = f2bf(rv - bf2f(rh));
            }
        }
        __syncthreads();   // CU-local: h_next complete before next step reads
    }
}

// ---------------------------------------------------------------------------
// logit[row] = Y2[row][:] . out_W + out_b, scattered to d_out[b][pos].
__global__ __launch_bounds__(256)
void gemv_out(const float* __restrict__ Y2, const float* __restrict__ outW,
              const float* __restrict__ outb, float* __restrict__ out, int row0) {
    int wave = threadIdx.x >> 6;
    int lane = threadIdx.x & 63;
    int row = blockIdx.x * 4 + wave;
    const float* y = Y2 + (size_t)row * H_;
    float4 v0 = *(const float4*)&y[lane * 4];
    float4 v1 = *(const float4*)&y[256 + lane * 4];
    float4 w0 = *(const float4*)&outW[lane * 4];
    float4 w1 = *(const float4*)&outW[256 + lane * 4];
    float s = v0.x * w0.x + v0.y * w0.y + v0.z * w0.z + v0.w * w0.w
            + v1.x * w1.x + v1.y * w1.y + v1.z * w1.z + v1.w * w1.w;
    #pragma unroll
    for (int off = 32; off > 0; off >>= 1) s += __shfl_down(s, off);
    if (lane == 0) {
        int r = row0 + row;
        int t = r / B_;
        int b = r - t * B_;
        int pos = (t == S_) ? 0 : t + 1;
        out[(size_t)b * OUTC_ + pos] = s + outb[0];
    }
}

// ---------------------------------------------------------------------------
__global__ __launch_bounds__(64)
void logsoftmax_rows(float* __restrict__ out) {
    int b = blockIdx.x;
    int lane = threadIdx.x;
    float* row = out + (size_t)b * OUTC_;
    float x0 = row[lane];
    float x1 = row[lane + 64];
    float x2 = (lane == 0) ? row[128] : -INFINITY;
    float m = fmaxf(fmaxf(x0, x1), x2);
    #pragma unroll
    for (int off = 32; off > 0; off >>= 1) m = fmaxf(m, __shfl_xor(m, off));
    float s = expf(x0 - m) + expf(x1 - m) + ((lane == 0) ? expf(x2 - m) : 0.f);
    #pragma unroll
    for (int off = 32; off > 0; off >>= 1) s += __shfl_xor(s, off);
    float ls = m + logf(s);
    row[lane] = x0 - ls;
    row[lane + 64] = x1 - ls;
    if (lane == 0) row[128] = x2 - ls;
}

// ---------------------------------------------------------------------------
extern "C" void kernel_launch(void* const* d_in, const int* in_sizes, int n_in,
                              void* d_out, int out_size, void* d_ws, size_t ws_size,
                              hipStream_t stream) {
    const int*   goal     = (const int*)d_in[0];
    const int*   stem     = (const int*)d_in[1];
    const float* stem_emb = (const float*)d_in[2];
    const float* word_emb = (const float*)d_in[3];
    const float* W_ih     = (const float*)d_in[4];
    const float* W_hh     = (const float*)d_in[5];
    const float* b_ih     = (const float*)d_in[6];
    const float* b_hh     = (const float*)d_in[7];
    const float* in_W     = (const float*)d_in[8];
    const float* in_b     = (const float*)d_in[9];
    const float* l0_W     = (const float*)d_in[10];
    const float* l0_b     = (const float*)d_in[11];
    const float* out_W    = (const float*)d_in[12];
    const float* out_b    = (const float*)d_in[13];
    float* out = (float*)d_out;

    // ~236 MB workspace layout (< proven-good 254 MB budget).
    char* base = (char*)d_ws;
    auto alloc = [&](size_t bytes) -> char* {
        char* p = base; base += (bytes + 255) & ~(size_t)255; return p;
    };
    // --- persistent region ---
    float* GW            = (float*)alloc((size_t)IV_ * H3_ * 4);           // 50.3 MB
    unsigned short* RHh  = (unsigned short*)alloc((size_t)(S_ + 1) * B_ * H_ * 2); // 67.7
    unsigned short* RHl  = (unsigned short*)alloc((size_t)(S_ + 1) * B_ * H_ * 2); // 67.7
    unsigned short* WHHh = (unsigned short*)alloc((size_t)H3_ * H_ * 2);   // 1.6
    unsigned short* WHHl = (unsigned short*)alloc((size_t)H3_ * H_ * 2);   // 1.6
    unsigned short* INWh = (unsigned short*)alloc((size_t)H_ * H_ * 2);
    unsigned short* INWl = (unsigned short*)alloc((size_t)H_ * H_ * 2);
    unsigned short* L0Wh = (unsigned short*)alloc((size_t)H_ * H_ * 2);
    unsigned short* L0Wl = (unsigned short*)alloc((size_t)H_ * H_ * 2);
    unsigned short* Hh0  = (unsigned short*)alloc((size_t)B_ * H_ * 2);
    unsigned short* Hl0  = (unsigned short*)alloc((size_t)B_ * H_ * 2);
    // --- union region: {RWE,WIH} (GW phase)  vs  {Y1,Y2} (MLP phase) ---
    char* uni = alloc((size_t)CHUNK_ * H_ * (2 + 2 + 4));                  // 45.1 MB
    unsigned short* RWEh = (unsigned short*)uni;
    unsigned short* RWEl = RWEh + (size_t)IV_ * H_;
    unsigned short* WIHh = RWEl + (size_t)IV_ * H_;
    unsigned short* WIHl = WIHh + (size_t)H3_ * H_;
    unsigned short* Y1h  = (unsigned short*)uni;
    unsigned short* Y1l  = Y1h + (size_t)CHUNK_ * H_;
    float* Y2            = (float*)(Y1l + (size_t)CHUNK_ * H_);

    // Splits of inputs
    split_f32<true ><<<(IV_ * H_ / 4) / 256, 256, 0, stream>>>(word_emb, RWEh, RWEl, IV_ * H_ / 4);
    split_f32<false><<<(H3_ * H_ / 4) / 256, 256, 0, stream>>>(W_ih, WIHh, WIHl, H3_ * H_ / 4);
    split_f32<false><<<(H3_ * H_ / 4) / 256, 256, 0, stream>>>(W_hh, WHHh, WHHl, H3_ * H_ / 4);
    split_f32<false><<<(H_ * H_ / 4) / 256, 256, 0, stream>>>(in_W, INWh, INWl, H_ * H_ / 4);
    split_f32<false><<<(H_ * H_ / 4) / 256, 256, 0, stream>>>(l0_W, L0Wh, L0Wl, H_ * H_ / 4);

    build_h0_split<<<(B_ * H_ / 4) / 256, 256, 0, stream>>>(stem, stem_emb, Hh0, Hl0);

    // GW = relu(word_emb) @ W_ih^T + b_ih   [8192 x 1536] f32
    gemm_split<0, false><<<dim3(H3_ / 128, IV_ / 128), 256, 0, stream>>>(
        RWEh, RWEl, WIHh, WIHl, b_ih, GW, nullptr, nullptr, IV_, H3_, H_);

    // Entire 129-step recurrence: batch-partitioned, block-local, NO global
    // sync. 32 blocks x 16 rows, 1024 threads.
    gru_local<<<B_ / 16, 1024, 0, stream>>>(
        goal, Hh0, Hl0, RHh, RHl, WHHh, WHHl, GW, b_hh);

    // MLP head over 66048 relu'd states, chunked 6x.
    for (int c = 0; c < NCHUNK_; ++c) {
        size_t ro = (size_t)c * CHUNK_ * H_;
        gemm_split<1, true><<<dim3(H_ / 128, CHUNK_ / 128), 256, 0, stream>>>(
            RHh + ro, RHl + ro, INWh, INWl, in_b, nullptr, Y1h, Y1l, CHUNK_, H_, H_);
        gemm_split<0, true><<<dim3(H_ / 128, CHUNK_ / 128), 256, 0, stream>>>(
            Y1h, Y1l, L0Wh, L0Wl, l0_b, Y2, nullptr, nullptr, CHUNK_, H_, H_);
        gemv_out<<<CHUNK_ / 4, 256, 0, stream>>>(Y2, out_W, out_b, out, c * CHUNK_);
    }

    logsoftmax_rows<<<B_, 64, 0, stream>>>(out);
}

// Round 10
// 6510.315 us; speedup vs baseline: 2.0454x; 1.9710x over previous
//
#include <hip/hip_runtime.h>
#include <math.h>

// Problem constants
#define B_    512
#define S_    128
#define H_    512
#define H3_   1536
#define IV_   8192
#define OUTC_ 129
#define CHUNK_ 11008       // 66048/6, divisible by 128
#define NCHUNK_ 6
#define EOS_  1

typedef __attribute__((ext_vector_type(8))) short  bf16x8;
typedef __attribute__((ext_vector_type(4))) float  f32x4;

__device__ inline unsigned short f2bf(float f) {
    union { float f; unsigned u; } x; x.f = f;
    unsigned r = x.u + 0x7FFF + ((x.u >> 16) & 1);   // RNE
    return (unsigned short)(r >> 16);
}
__device__ inline float bf2f(unsigned short b) {
    union { unsigned u; float f; } x; x.u = ((unsigned)b) << 16;
    return x.f;
}

// ---------------------------------------------------------------------------
// Generic f32 -> (hi,lo) bf16 split, optional relu first. n4 float4s.
template<bool RELU>
__global__ __launch_bounds__(256)
void split_f32(const float* __restrict__ src, unsigned short* __restrict__ hi,
               unsigned short* __restrict__ lo, int n4) {
    int i = blockIdx.x * 256 + threadIdx.x;
    if (i >= n4) return;
    float4 v = *(const float4*)&src[(size_t)i * 4];
    float a[4] = {v.x, v.y, v.z, v.w};
    size_t off = (size_t)i * 4;
    #pragma unroll
    for (int q = 0; q < 4; ++q) {
        float f = RELU ? fmaxf(a[q], 0.f) : a[q];
        unsigned short h = f2bf(f);
        hi[off + q] = h;
        lo[off + q] = f2bf(f - bf2f(h));
    }
}

// ---------------------------------------------------------------------------
// h0 gather + split
__global__ __launch_bounds__(256)
void build_h0_split(const int* __restrict__ stem, const float* __restrict__ stem_emb,
                    unsigned short* __restrict__ Hh, unsigned short* __restrict__ Hl) {
    int i = blockIdx.x * 256 + threadIdx.x;   // over B*H/4
    int b = i >> 7;
    int c = (i & 127) << 2;
    float4 v = *(const float4*)&stem_emb[(size_t)stem[b] * H_ + c];
    float a[4] = {v.x, v.y, v.z, v.w};
    size_t off = (size_t)b * H_ + c;
    #pragma unroll
    for (int q = 0; q < 4; ++q) {
        unsigned short h = f2bf(a[q]);
        Hh[off + q] = h;
        Hl[off + q] = f2bf(a[q] - bf2f(h));
    }
}

// ---------------------------------------------------------------------------
// Split-precision NT GEMM, 2-pass: C = (Ah+Al) @ Wh^T + bias (A-side split,
// W-side hi only — dropped A*W_lo term is ~2^-9 relative). A:[M,K], W:[N,K]
// bf16 planes. 128x128 tile, 256 thr. OUT_MODE 0: f32 C. 1: (hi,lo) planes.
template<int OUT_MODE, bool RELU_OUT>
__global__ __launch_bounds__(256)
void gemm_split(const unsigned short* __restrict__ Ah, const unsigned short* __restrict__ Al,
                const unsigned short* __restrict__ Wh,
                const float* __restrict__ bias,
                float* __restrict__ Cf, unsigned short* __restrict__ Chi,
                unsigned short* __restrict__ Clo, int M, int N, int K) {
    __shared__ unsigned short As[128][72];   // pad: 2-way bank alias (free)
    __shared__ unsigned short Ws[128][72];
    const int tid = threadIdx.x;
    const int bm = blockIdx.y * 128, bn = blockIdx.x * 128;
    const int wid = tid >> 6, lane = tid & 63;
    const int wm = (wid >> 1) * 64, wn = (wid & 1) * 64;
    const int lr = lane & 15, kg = (lane >> 4) * 8;

    f32x4 acc[4][4];
    #pragma unroll
    for (int i = 0; i < 4; ++i)
        #pragma unroll
        for (int j = 0; j < 4; ++j) acc[i][j] = f32x4{0.f, 0.f, 0.f, 0.f};

    for (int ph = 0; ph < 2; ++ph) {
        const unsigned short* Ap = (ph == 1) ? Al : Ah;
        for (int k0 = 0; k0 < K; k0 += 64) {
            int4 av[4], wv[4];
            #pragma unroll
            for (int s = 0; s < 4; ++s) {
                int seg = s * 256 + tid;            // 1024 16B segs per tile
                int row = seg >> 3, c8 = (seg & 7) * 8;
                av[s] = *(const int4*)&Ap[(size_t)(bm + row) * K + k0 + c8];
                wv[s] = *(const int4*)&Wh[(size_t)(bn + row) * K + k0 + c8];
            }
            __syncthreads();
            #pragma unroll
            for (int s = 0; s < 4; ++s) {
                int seg = s * 256 + tid;
                int row = seg >> 3, c8 = (seg & 7) * 8;
                *(int4*)&As[row][c8] = av[s];
                *(int4*)&Ws[row][c8] = wv[s];
            }
            __syncthreads();
            #pragma unroll
            for (int ks = 0; ks < 2; ++ks) {
                bf16x8 af[4], bfr[4];
                #pragma unroll
                for (int i = 0; i < 4; ++i)
                    af[i] = *(const bf16x8*)&As[wm + i * 16 + lr][ks * 32 + kg];
                #pragma unroll
                for (int j = 0; j < 4; ++j)
                    bfr[j] = *(const bf16x8*)&Ws[wn + j * 16 + lr][ks * 32 + kg];
                #pragma unroll
                for (int i = 0; i < 4; ++i)
                    #pragma unroll
                    for (int j = 0; j < 4; ++j)
                        acc[i][j] = __builtin_amdgcn_mfma_f32_16x16x32_bf16(
                            af[i], bfr[j], acc[i][j], 0, 0, 0);
            }
        }
    }

    const int r0 = (lane >> 4) * 4, cn = lane & 15;
    #pragma unroll
    for (int i = 0; i < 4; ++i) {
        #pragma unroll
        for (int j = 0; j < 4; ++j) {
            int colg = bn + wn + j * 16 + cn;
            float bv = bias[colg];
            #pragma unroll
            for (int rg = 0; rg < 4; ++rg) {
                int rowg = bm + wm + i * 16 + r0 + rg;
                float v = acc[i][j][rg] + bv;
                if (RELU_OUT) v = fmaxf(v, 0.f);
                size_t off = (size_t)rowg * N + colg;
                if (OUT_MODE == 0) {
                    Cf[off] = v;
                } else {
                    unsigned short h = f2bf(v);
                    Chi[off] = h;
                    Clo[off] = f2bf(v - bf2f(h));
                }
            }
        }
    }
}

// ---------------------------------------------------------------------------
// Block-local persistent GRU (round-9 structure + latency/BW fixes):
//  - goal slice staged in LDS once (kills per-step goal load chain)
//  - per-step GW gather (24 f32/thread) prefetched into registers BEFORE the
//    MFMA loop; consumed in epilogue -> ~900cyc HBM latency fully hidden
//  - W-side single bf16 plane (2-pass): halves the per-step L2 W-stream
//    (3.1 -> 1.55 MB), which is the per-CU BW floor (~150 GB/s/CU)
//  - W fragment loads software-pipelined (rotate next-kc ahead of MFMAs)
// 32 blocks x 1024 thr; h in LDS double-buffer; only CU-local syncthreads.
__global__ __launch_bounds__(1024)
void gru_local(const int* __restrict__ goal,
               const unsigned short* __restrict__ Hh0, const unsigned short* __restrict__ Hl0,
               unsigned short* __restrict__ RHh, unsigned short* __restrict__ RHl,
               const unsigned short* __restrict__ Wh,
               const float* __restrict__ GW, const float* __restrict__ b_hh) {
    __shared__ unsigned short hbuf[2][2][16][520];   // [buf][plane][row][col+pad]
    __shared__ int tokLds[16][130];                  // [row][t]
    const int tid = threadIdx.x;
    const int bm = blockIdx.x * 16;
    const int w = tid >> 6, lane = tid & 63;
    const int lr = lane & 15;           // A row / C col
    const int kg = (lane >> 4) * 8;     // k offset within 32-chunk
    const int r0 = (lane >> 4) * 4;     // C row base

    // Stage h0 (2048 16B segs over 1024 threads)
    #pragma unroll
    for (int s = 0; s < 2; ++s) {
        int idx = s * 1024 + tid;
        int plane = idx >> 10;
        int seg = idx & 1023;
        int r = seg >> 6, c8 = (seg & 63) * 8;
        const unsigned short* src = plane ? Hl0 : Hh0;
        *(int4*)&hbuf[0][plane][r][c8] = *(const int4*)&src[(size_t)(bm + r) * H_ + c8];
    }
    // Stage this block's token table (16 rows x 129 steps)
    for (int idx = tid; idx < 16 * 129; idx += 1024) {
        int r = idx / 129, t = idx - r * 129;
        tokLds[r][t] = (t < S_) ? goal[(bm + r) * S_ + t] : EOS_;
    }

    const int ja = (w * 2) * 16 + lr;        // j for tile 0
    const int jb = ja + 16;                  // j for tile 1
    const float bAr = b_hh[ja], bAz = b_hh[512 + ja], bAn = b_hh[1024 + ja];
    const float bBr = b_hh[jb], bBz = b_hh[512 + jb], bBn = b_hh[1024 + jb];
    __syncthreads();

    for (int t = 0; t <= S_; ++t) {
        const int p = t & 1;

        // Prefetch this step's GW gather into registers (independent of MFMA
        // work below; consumed only in the epilogues -> latency hidden).
        float gwv[2][4][3];
        #pragma unroll
        for (int rg = 0; rg < 4; ++rg) {
            const float* gw = GW + (size_t)tokLds[r0 + rg][t] * H3_;
            #pragma unroll
            for (int jj = 0; jj < 2; ++jj) {
                int j = jj ? jb : ja;
                gwv[jj][rg][0] = gw[j];
                gwv[jj][rg][1] = gw[512 + j];
                gwv[jj][rg][2] = gw[1024 + j];
            }
        }

        #pragma unroll
        for (int jj = 0; jj < 2; ++jj) {
            const int j = jj ? jb : ja;
            const float br = jj ? bBr : bAr;
            const float bz = jj ? bBz : bAz;
            const float bn = jj ? bBn : bAn;
            f32x4 acc0 = {0.f, 0.f, 0.f, 0.f};
            f32x4 acc1 = {0.f, 0.f, 0.f, 0.f};
            f32x4 acc2 = {0.f, 0.f, 0.f, 0.f};
            const unsigned short* wj = Wh + (size_t)j * H_ + kg;
            // Pipelined over kc: current W frags in w0..w2, next issued early.
            bf16x8 w0 = *(const bf16x8*)&wj[0];
            bf16x8 w1 = *(const bf16x8*)&wj[(size_t)512 * H_];
            bf16x8 w2 = *(const bf16x8*)&wj[(size_t)1024 * H_];
            #pragma unroll
            for (int kc = 0; kc < 16; ++kc) {
                bf16x8 c0 = w0, c1 = w1, c2 = w2;
                if (kc < 15) {   // issue next-kc loads ahead of the MFMAs
                    w0 = *(const bf16x8*)&wj[(kc + 1) * 32];
                    w1 = *(const bf16x8*)&wj[(size_t)512 * H_ + (kc + 1) * 32];
                    w2 = *(const bf16x8*)&wj[(size_t)1024 * H_ + (kc + 1) * 32];
                }
                bf16x8 ah = *(const bf16x8*)&hbuf[p][0][lr][kc * 32 + kg];
                bf16x8 al = *(const bf16x8*)&hbuf[p][1][lr][kc * 32 + kg];
                acc0 = __builtin_amdgcn_mfma_f32_16x16x32_bf16(ah, c0, acc0, 0, 0, 0);
                acc0 = __builtin_amdgcn_mfma_f32_16x16x32_bf16(al, c0, acc0, 0, 0, 0);
                acc1 = __builtin_amdgcn_mfma_f32_16x16x32_bf16(ah, c1, acc1, 0, 0, 0);
                acc1 = __builtin_amdgcn_mfma_f32_16x16x32_bf16(al, c1, acc1, 0, 0, 0);
                acc2 = __builtin_amdgcn_mfma_f32_16x16x32_bf16(ah, c2, acc2, 0, 0, 0);
                acc2 = __builtin_amdgcn_mfma_f32_16x16x32_bf16(al, c2, acc2, 0, 0, 0);
            }
            // Epilogue: gates for 4 rows x this j (GW values already in regs).
            #pragma unroll
            for (int rg = 0; rg < 4; ++rg) {
                int row = r0 + rg;
                int b = bm + row;
                float rr = 1.f / (1.f + expf(-(gwv[jj][rg][0] + acc0[rg] + br)));
                float zz = 1.f / (1.f + expf(-(gwv[jj][rg][1] + acc1[rg] + bz)));
                float nn = tanhf(gwv[jj][rg][2] + rr * (acc2[rg] + bn));
                float hp = bf2f(hbuf[p][0][row][j]) + bf2f(hbuf[p][1][row][j]);
                float hv = (1.f - zz) * nn + zz * hp;
                unsigned short hh = f2bf(hv);
                hbuf[p ^ 1][0][row][j] = hh;
                hbuf[p ^ 1][1][row][j] = f2bf(hv - bf2f(hh));
                float rv = fmaxf(hv, 0.f);
                unsigned short rh = f2bf(rv);
                size_t roff = ((size_t)t * B_ + b) * H_ + j;
                RHh[roff] = rh;
                RHl[roff] = f2bf(rv - bf2f(rh));
            }
        }
        __syncthreads();   // CU-local: h_next complete before next step reads
    }
}

// ---------------------------------------------------------------------------
// logit[row] = Y2[row][:] . out_W + out_b, scattered to d_out[b][pos].
__global__ __launch_bounds__(256)
void gemv_out(const float* __restrict__ Y2, const float* __restrict__ outW,
              const float* __restrict__ outb, float* __restrict__ out, int row0) {
    int wave = threadIdx.x >> 6;
    int lane = threadIdx.x & 63;
    int row = blockIdx.x * 4 + wave;
    const float* y = Y2 + (size_t)row * H_;
    float4 v0 = *(const float4*)&y[lane * 4];
    float4 v1 = *(const float4*)&y[256 + lane * 4];
    float4 w0 = *(const float4*)&outW[lane * 4];
    float4 w1 = *(const float4*)&outW[256 + lane * 4];
    float s = v0.x * w0.x + v0.y * w0.y + v0.z * w0.z + v0.w * w0.w
            + v1.x * w1.x + v1.y * w1.y + v1.z * w1.z + v1.w * w1.w;
    #pragma unroll
    for (int off = 32; off > 0; off >>= 1) s += __shfl_down(s, off);
    if (lane == 0) {
        int r = row0 + row;
        int t = r / B_;
        int b = r - t * B_;
        int pos = (t == S_) ? 0 : t + 1;
        out[(size_t)b * OUTC_ + pos] = s + outb[0];
    }
}

// ---------------------------------------------------------------------------
__global__ __launch_bounds__(64)
void logsoftmax_rows(float* __restrict__ out) {
    int b = blockIdx.x;
    int lane = threadIdx.x;
    float* row = out + (size_t)b * OUTC_;
    float x0 = row[lane];
    float x1 = row[lane + 64];
    float x2 = (lane == 0) ? row[128] : -INFINITY;
    float m = fmaxf(fmaxf(x0, x1), x2);
    #pragma unroll
    for (int off = 32; off > 0; off >>= 1) m = fmaxf(m, __shfl_xor(m, off));
    float s = expf(x0 - m) + expf(x1 - m) + ((lane == 0) ? expf(x2 - m) : 0.f);
    #pragma unroll
    for (int off = 32; off > 0; off >>= 1) s += __shfl_xor(s, off);
    float ls = m + logf(s);
    row[lane] = x0 - ls;
    row[lane + 64] = x1 - ls;
    if (lane == 0) row[128] = x2 - ls;
}

// ---------------------------------------------------------------------------
extern "C" void kernel_launch(void* const* d_in, const int* in_sizes, int n_in,
                              void* d_out, int out_size, void* d_ws, size_t ws_size,
                              hipStream_t stream) {
    const int*   goal     = (const int*)d_in[0];
    const int*   stem     = (const int*)d_in[1];
    const float* stem_emb = (const float*)d_in[2];
    const float* word_emb = (const float*)d_in[3];
    const float* W_ih     = (const float*)d_in[4];
    const float* W_hh     = (const float*)d_in[5];
    const float* b_ih     = (const float*)d_in[6];
    const float* b_hh     = (const float*)d_in[7];
    const float* in_W     = (const float*)d_in[8];
    const float* in_b     = (const float*)d_in[9];
    const float* l0_W     = (const float*)d_in[10];
    const float* l0_b     = (const float*)d_in[11];
    const float* out_W    = (const float*)d_in[12];
    const float* out_b    = (const float*)d_in[13];
    float* out = (float*)d_out;

    // ~233 MB workspace layout (< proven-good 254 MB budget).
    char* base = (char*)d_ws;
    auto alloc = [&](size_t bytes) -> char* {
        char* p = base; base += (bytes + 255) & ~(size_t)255; return p;
    };
    // --- persistent region ---
    float* GW            = (float*)alloc((size_t)IV_ * H3_ * 4);           // 50.3 MB
    unsigned short* RHh  = (unsigned short*)alloc((size_t)(S_ + 1) * B_ * H_ * 2); // 67.7
    unsigned short* RHl  = (unsigned short*)alloc((size_t)(S_ + 1) * B_ * H_ * 2); // 67.7
    unsigned short* WHHh = (unsigned short*)alloc((size_t)H3_ * H_ * 2);   // 1.6
    unsigned short* WHHl = (unsigned short*)alloc((size_t)H3_ * H_ * 2);   // (unused W-lo)
    unsigned short* INWh = (unsigned short*)alloc((size_t)H_ * H_ * 2);
    unsigned short* INWl = (unsigned short*)alloc((size_t)H_ * H_ * 2);
    unsigned short* L0Wh = (unsigned short*)alloc((size_t)H_ * H_ * 2);
    unsigned short* L0Wl = (unsigned short*)alloc((size_t)H_ * H_ * 2);
    unsigned short* Hh0  = (unsigned short*)alloc((size_t)B_ * H_ * 2);
    unsigned short* Hl0  = (unsigned short*)alloc((size_t)B_ * H_ * 2);
    // --- union region: {RWE,WIH} (GW phase)  vs  {Y1,Y2} (MLP phase) ---
    char* uni = alloc((size_t)CHUNK_ * H_ * (2 + 2 + 4));                  // 45.1 MB
    unsigned short* RWEh = (unsigned short*)uni;
    unsigned short* RWEl = RWEh + (size_t)IV_ * H_;
    unsigned short* WIHh = RWEl + (size_t)IV_ * H_;
    unsigned short* WIHl = WIHh + (size_t)H3_ * H_;
    unsigned short* Y1h  = (unsigned short*)uni;
    unsigned short* Y1l  = Y1h + (size_t)CHUNK_ * H_;
    float* Y2            = (float*)(Y1l + (size_t)CHUNK_ * H_);

    // Splits of inputs (lo planes of W matrices are written but unread now)
    split_f32<true ><<<(IV_ * H_ / 4) / 256, 256, 0, stream>>>(word_emb, RWEh, RWEl, IV_ * H_ / 4);
    split_f32<false><<<(H3_ * H_ / 4) / 256, 256, 0, stream>>>(W_ih, WIHh, WIHl, H3_ * H_ / 4);
    split_f32<false><<<(H3_ * H_ / 4) / 256, 256, 0, stream>>>(W_hh, WHHh, WHHl, H3_ * H_ / 4);
    split_f32<false><<<(H_ * H_ / 4) / 256, 256, 0, stream>>>(in_W, INWh, INWl, H_ * H_ / 4);
    split_f32<false><<<(H_ * H_ / 4) / 256, 256, 0, stream>>>(l0_W, L0Wh, L0Wl, H_ * H_ / 4);

    build_h0_split<<<(B_ * H_ / 4) / 256, 256, 0, stream>>>(stem, stem_emb, Hh0, Hl0);

    // GW = relu(word_emb) @ W_ih^T + b_ih   [8192 x 1536] f32
    gemm_split<0, false><<<dim3(H3_ / 128, IV_ / 128), 256, 0, stream>>>(
        RWEh, RWEl, WIHh, b_ih, GW, nullptr, nullptr, IV_, H3_, H_);

    // Entire 129-step recurrence: batch-partitioned, block-local, NO global
    // sync. 32 blocks x 16 rows, 1024 threads.
    gru_local<<<B_ / 16, 1024, 0, stream>>>(
        goal, Hh0, Hl0, RHh, RHl, WHHh, GW, b_hh);

    // MLP head over 66048 relu'd states, chunked 6x.
    for (int c = 0; c < NCHUNK_; ++c) {
        size_t ro = (size_t)c * CHUNK_ * H_;
        gemm_split<1, true><<<dim3(H_ / 128, CHUNK_ / 128), 256, 0, stream>>>(
            RHh + ro, RHl + ro, INWh, in_b, nullptr, Y1h, Y1l, CHUNK_, H_, H_);
        gemm_split<0, true><<<dim3(H_ / 128, CHUNK_ / 128), 256, 0, stream>>>(
            Y1h, Y1l, L0Wh, l0_b, Y2, nullptr, nullptr, CHUNK_, H_, H_);
        gemv_out<<<CHUNK_ / 4, 256, 0, stream>>>(Y2, out_W, out_b, out, c * CHUNK_);
    }

    logsoftmax_rows<<<B_, 64, 0, stream>>>(out);
}